// Round 8
// baseline (1723.417 us; speedup 1.0000x reference)
//
#include <hip/hip_runtime.h>
#include <math.h>

#define BATCH   512
#define TSTEPS  3600
#define H       64
#define XCHUNK  8
#define CLASSES 5

typedef float v2f __attribute__((ext_vector_type(2)));

__device__ __forceinline__ float bcf(int v)   { return __builtin_bit_cast(float, v); }
__device__ __forceinline__ int   bci(float v) { return __builtin_bit_cast(int, v); }
__device__ __forceinline__ float lane_bcast(float v, int l) {
    return bcf(__builtin_amdgcn_readlane(bci(v), l));
}

__device__ __forceinline__ float fast_sigmoid(float x) {
    float e = __expf(-x);
    return __builtin_amdgcn_rcpf(1.0f + e);
}
__device__ __forceinline__ float fast_tanh(float x) {
    float e = __expf(2.0f * x);        // |2x| small by construction
    return (e - 1.0f) * __builtin_amdgcn_rcpf(e + 1.0f);
}

// ONE WAVE per batch. h broadcast via XOR-SWIZZLE family: hv[v] = h_{lane^v},
// v=0..63, built from 1 ds_bpermute (xor 32) + 62 ds_swizzle (xor 1..31 on
// each half-family). Crossbar ops only - no LDS allocation, no memory, no
// serial chain (unlike R5 DPP), and results are VGPRs that feed v_pk_fma_f32
// natively (unlike R6/R7 readlane->SGPR, which the compiler repacked through
// v_movs). Weights are gathered ONCE pre-permuted to the xor schedule:
// wp[g][k] = {W[g*64+lane][lane^2k], W[g*64+lane][lane^(2k+1)]}.
// Software pipeline: issue next group's 8 swizzles, then consume previous
// group's 12 pk_fmas -> ~8 DS ops in flight, swizzle latency hidden, VGPR
// peak ~235. This is a latency race (512 serial chains, 1024 SIMDs).
#define SWZI(vv) bcf(__builtin_amdgcn_ds_swizzle(hi32, (((vv) & 31) << 10) | 0x1F))
#define SWZS(vv) bcf(__builtin_amdgcn_ds_swizzle(hs32, (((vv) & 31) << 10) | 0x1F))

__global__ __launch_bounds__(64, 1) void gru_swz_kernel(
    const float* __restrict__ x,      // [B, T, 1]
    const float* __restrict__ w_ih,   // [192, 1]
    const float* __restrict__ w_hh,   // [192, 64]
    const float* __restrict__ b_ih,   // [192]
    const float* __restrict__ b_hh,   // [192]
    const float* __restrict__ w_head, // [5, 64]
    const float* __restrict__ b_head, // [5]
    float* __restrict__ out)          // [B, 5]
{
    const int lane = threadIdx.x;    // block = 1 wave
    const int b    = blockIdx.x;

    // --- weights pre-permuted for the xor broadcast schedule ---
    const float* r0 = w_hh + (0 * H + lane) * H;
    const float* r1 = w_hh + (1 * H + lane) * H;
    const float* r2 = w_hh + (2 * H + lane) * H;
    v2f wp0[32], wp1[32], wp2[32];
#pragma unroll
    for (int k = 0; k < 32; ++k) {
        const int va = lane ^ (2 * k), vb = lane ^ (2 * k + 1);
        wp0[k] = (v2f){r0[va], r0[vb]};
        wp1[k] = (v2f){r1[va], r1[vb]};
        wp2[k] = (v2f){r2[va], r2[vb]};
    }

    const float wih_r = w_ih[lane], wih_z = w_ih[H + lane], wih_n = w_ih[2 * H + lane];
    const float bih_r = b_ih[lane], bih_z = b_ih[H + lane], bih_n = b_ih[2 * H + lane];
    const float bhh_r = b_hh[lane], bhh_z = b_hh[H + lane], bhh_n = b_hh[2 * H + lane];

    const int addr32 = (lane ^ 32) << 2;   // bpermute byte address: lane^32

    float h_reg = 0.0f;
    const float* xb = x + (size_t)b * TSTEPS;
    float xv = xb[lane & 7];               // first x-chunk (8 uniform values in lanes)

    for (int tc = 0; tc < TSTEPS / XCHUNK; ++tc) {
        int noff = (tc + 1) * XCHUNK;
        if (noff >= TSTEPS) noff = 0;
        const float xvn = xb[noff + (lane & 7)];   // prefetch next chunk

#pragma unroll
        for (int tt = 0; tt < XCHUNK; ++tt) {
            const float xt = lane_bcast(xv, tt);   // SGPR; consumed ~180 instrs later
            const int hi32 = bci(h_reg);
            const int hs32 = __builtin_amdgcn_ds_bpermute(addr32, hi32); // h_{lane^32}

            v2f ar = (v2f){bhh_r, 0.f};
            v2f az = (v2f){bhh_z, 0.f};
            v2f an = (v2f){bhh_n, 0.f};
            v2f A0, A1, A2, A3, B0, B1, B2, B3;

#define CONS(k0, P0, P1, P2, P3)                                          \
            ar = __builtin_elementwise_fma(wp0[k0 + 0], P0, ar);          \
            az = __builtin_elementwise_fma(wp1[k0 + 0], P0, az);          \
            an = __builtin_elementwise_fma(wp2[k0 + 0], P0, an);          \
            ar = __builtin_elementwise_fma(wp0[k0 + 1], P1, ar);          \
            az = __builtin_elementwise_fma(wp1[k0 + 1], P1, az);          \
            an = __builtin_elementwise_fma(wp2[k0 + 1], P1, an);          \
            ar = __builtin_elementwise_fma(wp0[k0 + 2], P2, ar);          \
            az = __builtin_elementwise_fma(wp1[k0 + 2], P2, az);          \
            an = __builtin_elementwise_fma(wp2[k0 + 2], P2, an);          \
            ar = __builtin_elementwise_fma(wp0[k0 + 3], P3, ar);          \
            az = __builtin_elementwise_fma(wp1[k0 + 3], P3, az);          \
            an = __builtin_elementwise_fma(wp2[k0 + 3], P3, an);

            // G0: v = 0..7
            A0.x = h_reg;     A0.y = SWZI(1);
            A1.x = SWZI(2);   A1.y = SWZI(3);
            A2.x = SWZI(4);   A2.y = SWZI(5);
            A3.x = SWZI(6);   A3.y = SWZI(7);
            // G1: v = 8..15
            B0.x = SWZI(8);   B0.y = SWZI(9);
            B1.x = SWZI(10);  B1.y = SWZI(11);
            B2.x = SWZI(12);  B2.y = SWZI(13);
            B3.x = SWZI(14);  B3.y = SWZI(15);
            CONS(0, A0, A1, A2, A3)
            // G2: v = 16..23
            A0.x = SWZI(16);  A0.y = SWZI(17);
            A1.x = SWZI(18);  A1.y = SWZI(19);
            A2.x = SWZI(20);  A2.y = SWZI(21);
            A3.x = SWZI(22);  A3.y = SWZI(23);
            CONS(4, B0, B1, B2, B3)
            // G3: v = 24..31
            B0.x = SWZI(24);  B0.y = SWZI(25);
            B1.x = SWZI(26);  B1.y = SWZI(27);
            B2.x = SWZI(28);  B2.y = SWZI(29);
            B3.x = SWZI(30);  B3.y = SWZI(31);
            CONS(8, A0, A1, A2, A3)
            // G4: v = 32..39  (hs family: h_{lane^32^u})
            A0.x = bcf(hs32); A0.y = SWZS(1);
            A1.x = SWZS(2);   A1.y = SWZS(3);
            A2.x = SWZS(4);   A2.y = SWZS(5);
            A3.x = SWZS(6);   A3.y = SWZS(7);
            CONS(12, B0, B1, B2, B3)
            // G5: v = 40..47
            B0.x = SWZS(8);   B0.y = SWZS(9);
            B1.x = SWZS(10);  B1.y = SWZS(11);
            B2.x = SWZS(12);  B2.y = SWZS(13);
            B3.x = SWZS(14);  B3.y = SWZS(15);
            CONS(16, A0, A1, A2, A3)
            // G6: v = 48..55
            A0.x = SWZS(16);  A0.y = SWZS(17);
            A1.x = SWZS(18);  A1.y = SWZS(19);
            A2.x = SWZS(20);  A2.y = SWZS(21);
            A3.x = SWZS(22);  A3.y = SWZS(23);
            CONS(20, B0, B1, B2, B3)
            // G7: v = 56..63
            B0.x = SWZS(24);  B0.y = SWZS(25);
            B1.x = SWZS(26);  B1.y = SWZS(27);
            B2.x = SWZS(28);  B2.y = SWZS(29);
            B3.x = SWZS(30);  B3.y = SWZS(31);
            CONS(24, A0, A1, A2, A3)
            CONS(28, B0, B1, B2, B3)
#undef CONS

            const float dr = ar.x + ar.y;
            const float dz = az.x + az.y;
            const float dn = an.x + an.y;

            const float r = fast_sigmoid(fmaf(xt, wih_r, bih_r) + dr);
            const float z = fast_sigmoid(fmaf(xt, wih_z, bih_z) + dz);
            const float n = fast_tanh(fmaf(xt, wih_n, bih_n) + r * dn);
            h_reg = fmaf(z, h_reg - n, n);   // (1-z)*n + z*h
        }
        xv = xvn;
    }

    // ---- head: out[b][c] = w_head[c,:] . h + b_head[c] ----
#pragma unroll
    for (int cc = 0; cc < CLASSES; ++cc) {
        float v = h_reg * w_head[cc * H + lane];
#pragma unroll
        for (int off = 32; off > 0; off >>= 1)
            v += __shfl_down(v, off, 64);
        if (lane == 0) out[b * CLASSES + cc] = v + b_head[cc];
    }
}

extern "C" void kernel_launch(void* const* d_in, const int* in_sizes, int n_in,
                              void* d_out, int out_size, void* d_ws, size_t ws_size,
                              hipStream_t stream) {
    const float* x      = (const float*)d_in[0];
    const float* w_ih   = (const float*)d_in[1];
    const float* w_hh   = (const float*)d_in[2];
    const float* b_ih   = (const float*)d_in[3];
    const float* b_hh   = (const float*)d_in[4];
    const float* w_head = (const float*)d_in[5];
    const float* b_head = (const float*)d_in[6];
    float* out = (float*)d_out;

    gru_swz_kernel<<<BATCH, 64, 0, stream>>>(x, w_ih, w_hh, b_ih, b_hh,
                                             w_head, b_head, out);
}

// Round 10
// 1226.875 us; speedup vs baseline: 1.4047x; 1.4047x over previous
//
#include <hip/hip_runtime.h>
#include <math.h>

#define BATCH   512
#define TSTEPS  3600
#define H       64
#define XCHUNK  16
#define NCHUNK  (TSTEPS / XCHUNK)   // 225
#define CLASSES 5

typedef _Float16 h2 __attribute__((ext_vector_type(2)));

__device__ __forceinline__ h2 bc_h2(unsigned int v) {
    return __builtin_bit_cast(h2, v);
}

__device__ __forceinline__ float fast_sigmoid(float x) {
    float e = __expf(-x);                 // |x| <= ~9 by construction
    return __builtin_amdgcn_rcpf(1.0f + e);
}
__device__ __forceinline__ float fast_tanh(float x) {
    float e = __expf(2.0f * x);           // |2x| <= ~18, no overflow
    return (e - 1.0f) * __builtin_amdgcn_rcpf(e + 1.0f);
}

// ONE WAVE per batch. Dot inputs in FP16 (threshold 4.6e-3; fp32 ran at
// 1e-8 - spend precision to shrink the broadcast): h published to LDS as
// f16, read back as EIGHT wave-uniform ds_read_b128 - each landed dword is
// natively the {h_2u, h_2u+1} operand of v_dot2_f32_f16 (no repack movs,
// 2 MACs/instr, weights halved to 96 VGPRs so all 8 reads pipeline).
// R9 BUG FIXED HERE: the f16 store and uint4 loads are TBAA-distinct, so
// the compiler treated them as non-aliasing and let reads escape their
// ordering -> output depended on leftover LDS from the previous launch
// (first call passed, graph replays diverged). An asm memory clobber
// between store and loads pins the order and makes the store live; hl is
// also zero-initialized so no path can see LDS history.
__global__ __launch_bounds__(64, 1) void gru_dot2_kernel(
    const float* __restrict__ x,      // [B, T, 1]
    const float* __restrict__ w_ih,   // [192, 1]
    const float* __restrict__ w_hh,   // [192, 64]
    const float* __restrict__ b_ih,   // [192]
    const float* __restrict__ b_hh,   // [192]
    const float* __restrict__ w_head, // [5, 64]
    const float* __restrict__ b_head, // [5]
    float* __restrict__ out)          // [B, 5]
{
    __shared__ __align__(16) _Float16 hl[H];

    const int lane = threadIdx.x;    // block = 1 wave
    const int b    = blockIdx.x;

    // --- recurrent weights as f16 pairs: wg[u] = {row[2u], row[2u+1]} ---
    const float* r0 = w_hh + (0 * H + lane) * H;
    const float* r1 = w_hh + (1 * H + lane) * H;
    const float* r2 = w_hh + (2 * H + lane) * H;
    h2 wr[32], wz[32], wn[32];
#pragma unroll
    for (int u = 0; u < 32; ++u) {
        wr[u] = (h2){(_Float16)r0[2 * u], (_Float16)r0[2 * u + 1]};
        wz[u] = (h2){(_Float16)r1[2 * u], (_Float16)r1[2 * u + 1]};
        wn[u] = (h2){(_Float16)r2[2 * u], (_Float16)r2[2 * u + 1]};
    }

    const float wih_r = w_ih[lane], wih_z = w_ih[H + lane], wih_n = w_ih[2 * H + lane];
    const float bih_r = b_ih[lane], bih_z = b_ih[H + lane], bih_n = b_ih[2 * H + lane];
    const float bhh_r = b_hh[lane], bhh_z = b_hh[H + lane], bhh_n = b_hh[2 * H + lane];

    float h_reg = 0.0f;
    const float* xb = x + (size_t)b * TSTEPS;

    // deterministic LDS start state (h0 = 0)
    hl[lane] = (_Float16)0.0f;
    __asm volatile("" ::: "memory");

    // x double-buffer: current chunk in xc, prefetch next into xn
    float xc[XCHUNK], xn[XCHUNK];
#pragma unroll
    for (int k = 0; k < XCHUNK; ++k) xc[k] = xb[k];

    for (int tc = 0; tc < NCHUNK; ++tc) {
        const float* nb = xb + ((tc + 1 < NCHUNK) ? (tc + 1) * XCHUNK : 0);
#pragma unroll
        for (int k = 0; k < XCHUNK; ++k) xn[k] = nb[k];

#pragma unroll
        for (int tt = 0; tt < XCHUNK; ++tt) {
            // publish h as f16; clobber pins store<->load order (TBAA fix)
            hl[lane] = (_Float16)h_reg;
            __asm volatile("" ::: "memory");

            const uint4* hp = (const uint4*)hl;   // wave-uniform broadcast
            const uint4 q0 = hp[0], q1 = hp[1], q2 = hp[2], q3 = hp[3];
            const uint4 q4 = hp[4], q5 = hp[5], q6 = hp[6], q7 = hp[7];

            float ar = bhh_r, az = bhh_z, an = bhh_n;

#define RND(u, P)                                               \
            ar = __builtin_amdgcn_fdot2(wr[u], (P), ar, false); \
            az = __builtin_amdgcn_fdot2(wz[u], (P), az, false); \
            an = __builtin_amdgcn_fdot2(wn[u], (P), an, false);

            RND(0,  bc_h2(q0.x)) RND(1,  bc_h2(q0.y)) RND(2,  bc_h2(q0.z)) RND(3,  bc_h2(q0.w))
            RND(4,  bc_h2(q1.x)) RND(5,  bc_h2(q1.y)) RND(6,  bc_h2(q1.z)) RND(7,  bc_h2(q1.w))
            RND(8,  bc_h2(q2.x)) RND(9,  bc_h2(q2.y)) RND(10, bc_h2(q2.z)) RND(11, bc_h2(q2.w))
            RND(12, bc_h2(q3.x)) RND(13, bc_h2(q3.y)) RND(14, bc_h2(q3.z)) RND(15, bc_h2(q3.w))
            RND(16, bc_h2(q4.x)) RND(17, bc_h2(q4.y)) RND(18, bc_h2(q4.z)) RND(19, bc_h2(q4.w))
            RND(20, bc_h2(q5.x)) RND(21, bc_h2(q5.y)) RND(22, bc_h2(q5.z)) RND(23, bc_h2(q5.w))
            RND(24, bc_h2(q6.x)) RND(25, bc_h2(q6.y)) RND(26, bc_h2(q6.z)) RND(27, bc_h2(q6.w))
            RND(28, bc_h2(q7.x)) RND(29, bc_h2(q7.y)) RND(30, bc_h2(q7.z)) RND(31, bc_h2(q7.w))
#undef RND

            const float xt = xc[tt];
            const float r = fast_sigmoid(fmaf(xt, wih_r, bih_r) + ar);
            const float z = fast_sigmoid(fmaf(xt, wih_z, bih_z) + az);
            const float n = fast_tanh(fmaf(xt, wih_n, bih_n) + r * an);
            h_reg = fmaf(z, h_reg - n, n);   // (1-z)*n + z*h
        }

#pragma unroll
        for (int k = 0; k < XCHUNK; ++k) xc[k] = xn[k];
    }

    // ---- head: out[b][c] = w_head[c,:] . h + b_head[c] ----
#pragma unroll
    for (int cc = 0; cc < CLASSES; ++cc) {
        float v = h_reg * w_head[cc * H + lane];
#pragma unroll
        for (int off = 32; off > 0; off >>= 1)
            v += __shfl_down(v, off, 64);
        if (lane == 0) out[b * CLASSES + cc] = v + b_head[cc];
    }
}

extern "C" void kernel_launch(void* const* d_in, const int* in_sizes, int n_in,
                              void* d_out, int out_size, void* d_ws, size_t ws_size,
                              hipStream_t stream) {
    const float* x      = (const float*)d_in[0];
    const float* w_ih   = (const float*)d_in[1];
    const float* w_hh   = (const float*)d_in[2];
    const float* b_ih   = (const float*)d_in[3];
    const float* b_hh   = (const float*)d_in[4];
    const float* w_head = (const float*)d_in[5];
    const float* b_head = (const float*)d_in[6];
    float* out = (float*)d_out;

    gru_dot2_kernel<<<BATCH, 64, 0, stream>>>(x, w_ih, w_hh, b_ih, b_hh,
                                              w_head, b_head, out);
}